// Round 2
// baseline (2796.387 us; speedup 1.0000x reference)
//
#include <hip/hip_runtime.h>
#include <hip/hip_bf16.h>
#include <math.h>

#define NP 500000
#define NQ 200000
#define C 64
#define NE 1200000

// ---------------- kernels ----------------

// wv[k] = sum_j Wd[k][j] * avd[j]   (folds hd @ avd into x_dst @ wv)
__global__ void wdavd_kernel(const float* __restrict__ Wd,
                             const float* __restrict__ avd,
                             float* __restrict__ wv) {
    int k = threadIdx.x;
    if (k < C) {
        float acc = 0.f;
        #pragma unroll
        for (int j = 0; j < C; ++j) acc = fmaf(Wd[k * C + j], avd[j], acc);
        wv[k] = acc;
    }
}

// hs = x @ W (row per wave, lane = output column), fused al_s = hs . avs
__global__ void __launch_bounds__(256) hs_kernel(
        const float* __restrict__ x, const float* __restrict__ W,
        const float* __restrict__ avs,
        __hip_bfloat16* __restrict__ hs, float* __restrict__ al_s, int Ns) {
    __shared__ float Wl[C * C];
    __shared__ float al[C];
    for (int i = threadIdx.x; i < C * C; i += 256) Wl[i] = W[i];
    if (threadIdx.x < C) al[threadIdx.x] = avs[threadIdx.x];
    __syncthreads();
    int lane = threadIdx.x & 63;
    int wid  = (blockIdx.x * 256 + threadIdx.x) >> 6;
    int nw   = (gridDim.x * 256) >> 6;
    for (int row = wid; row < Ns; row += nw) {
        const float* xr = x + (size_t)row * C;
        float acc = 0.f;
        #pragma unroll
        for (int k = 0; k < C; ++k) acc = fmaf(xr[k], Wl[k * C + lane], acc);
        hs[(size_t)row * C + lane] = __float2bfloat16(acc);
        float v = acc * al[lane];
        #pragma unroll
        for (int off = 32; off >= 1; off >>= 1) v += __shfl_xor(v, off);
        if (lane == 0) al_s[row] = v;
    }
}

// al_d[row] = dot(x_dst[row], wv)
__global__ void __launch_bounds__(256) ald_kernel(
        const float* __restrict__ x, const float* __restrict__ wv,
        float* __restrict__ al_d, int Nd) {
    __shared__ float w[C];
    if (threadIdx.x < C) w[threadIdx.x] = wv[threadIdx.x];
    __syncthreads();
    int lane = threadIdx.x & 63;
    int wid  = (blockIdx.x * 256 + threadIdx.x) >> 6;
    int nw   = (gridDim.x * 256) >> 6;
    for (int row = wid; row < Nd; row += nw) {
        float v = x[(size_t)row * C + lane] * w[lane];
        #pragma unroll
        for (int off = 32; off >= 1; off >>= 1) v += __shfl_xor(v, off);
        if (lane == 0) al_d[row] = v;
    }
}

// per edge: e = leaky_relu(al_s[src]+al_d[dst]); ex = exp(e); den[dst] += ex
// (segment-max skipped: softmax is shift-invariant and |e| is small here)
__global__ void __launch_bounds__(256) edge1_kernel(
        const int* __restrict__ src, const int* __restrict__ dst,
        const float* __restrict__ al_s, const float* __restrict__ al_d,
        float* __restrict__ exb, float* __restrict__ den) {
    int e = blockIdx.x * 256 + threadIdx.x;
    if (e >= NE) return;
    int s = src[e], d = dst[e];
    float v = al_s[s] + al_d[d];
    v = v > 0.f ? v : 0.2f * v;
    float xv = expf(v);
    exb[e] = xv;
    atomicAdd(&den[d], xv);
}

// per edge (one wave, lane = channel): agg[dst] += (ex/den[dst]) * hs[src]
__global__ void __launch_bounds__(256) edge2_kernel(
        const int* __restrict__ src, const int* __restrict__ dst,
        const float* __restrict__ exb, const float* __restrict__ den,
        const __hip_bfloat16* __restrict__ hs, float* __restrict__ agg) {
    int lane = threadIdx.x & 63;
    int e = (blockIdx.x * 256 + threadIdx.x) >> 6;
    if (e >= NE) return;
    int s = src[e], d = dst[e];
    float alpha = exb[e] / den[d];
    float v = alpha * __bfloat162float(hs[(size_t)s * C + lane]);
    atomicAdd(&agg[(size_t)d * C + lane], v);
}

// finish: in place fp32, += bias then ELU (used after every conv; the
// mid-layer ELU and the final ELU coincide for this 2-layer net)
__global__ void __launch_bounds__(256) finish_f32_kernel(
        float* __restrict__ agg, const float* __restrict__ bias, int n) {
    int i = blockIdx.x * 256 + threadIdx.x;
    int stride = gridDim.x * 256;
    for (; i < n; i += stride) {
        float v = agg[i] + bias[i & (C - 1)];
        agg[i] = v > 0.f ? v : expm1f(v);
    }
}

// ---------------- host ----------------

static inline int imin(int a, int b) { return a < b ? a : b; }

extern "C" void kernel_launch(void* const* d_in, const int* in_sizes, int n_in,
                              void* d_out, int out_size, void* d_ws, size_t ws_size,
                              hipStream_t stream) {
    const float* x_person  = (const float*)d_in[0];
    const float* x_product = (const float*)d_in[1];
    const int* pv_src = (const int*)d_in[2];
    const int* pv_dst = (const int*)d_in[3];
    const int* vp_src = (const int*)d_in[4];
    const int* vp_dst = (const int*)d_in[5];
    const float* W_src = (const float*)d_in[6];
    const float* W_dst = (const float*)d_in[7];
    const float* a_src = (const float*)d_in[8];
    const float* a_dst = (const float*)d_in[9];
    const float* bias  = (const float*)d_in[10];

    // ---- workspace layout (~250 MB) ----
    float* hp1 = (float*)d_ws;                                    // NP*C fp32
    float* hq1 = hp1 + (size_t)NP * C;                            // NQ*C fp32
    __hip_bfloat16* hs = (__hip_bfloat16*)(hq1 + (size_t)NQ * C); // NP*C bf16
    float* den  = (float*)(hs + (size_t)NP * C);                  // NP
    float* al_s = den + NP;                                       // NP
    float* al_d = al_s + NP;                                      // NP
    float* exb  = al_d + NP;                                      // NE
    float* wv   = exb + NE;                                       // C

    float* out_hp = (float*)d_out;                                // NP*C fp32
    float* out_hq = out_hp + (size_t)NP * C;                      // NQ*C fp32

    auto run_conv = [&](const float* xsrc, int Ns, const float* xdst, int Nd,
                        const int* esrc, const int* edst,
                        int l, int et, float* aggbuf) {
        const float* Ws  = W_src + (size_t)(l * 2 + et) * C * C;
        const float* Wd  = W_dst + (size_t)(l * 2 + et) * C * C;
        const float* avs = a_src + (size_t)(l * 2 + et) * C;
        const float* avd = a_dst + (size_t)(l * 2 + et) * C;

        hipMemsetAsync(den, 0, (size_t)Nd * sizeof(float), stream);
        hipMemsetAsync(aggbuf, 0, (size_t)Nd * C * sizeof(float), stream);

        wdavd_kernel<<<1, 64, 0, stream>>>(Wd, avd, wv);
        hs_kernel<<<imin((Ns + 3) / 4, 2048), 256, 0, stream>>>(xsrc, Ws, avs, hs, al_s, Ns);
        ald_kernel<<<imin((Nd + 3) / 4, 2048), 256, 0, stream>>>(xdst, wv, al_d, Nd);
        edge1_kernel<<<(NE + 255) / 256, 256, 0, stream>>>(esrc, edst, al_s, al_d, exb, den);
        edge2_kernel<<<NE / 4, 256, 0, stream>>>(esrc, edst, exb, den, hs, aggbuf);
    };

    // ---- layer 0 (inputs: d_in x tensors; outputs hq1/hp1, ELU applied) ----
    run_conv(x_person, NP, x_product, NQ, pv_src, pv_dst, 0, 0, hq1);
    finish_f32_kernel<<<2048, 256, 0, stream>>>(hq1, bias + 0 * C, NQ * C);
    run_conv(x_product, NQ, x_person, NP, vp_src, vp_dst, 0, 1, hp1);
    finish_f32_kernel<<<2048, 256, 0, stream>>>(hp1, bias + 1 * C, NP * C);

    // ---- layer 1 (inputs hp1/hq1; aggregate straight into fp32 d_out) ----
    run_conv(hp1, NP, hq1, NQ, pv_src, pv_dst, 1, 0, out_hq);
    finish_f32_kernel<<<2048, 256, 0, stream>>>(out_hq, bias + 2 * C, NQ * C);
    run_conv(hq1, NQ, hp1, NP, vp_src, vp_dst, 1, 1, out_hp);
    finish_f32_kernel<<<2048, 256, 0, stream>>>(out_hp, bias + 3 * C, NP * C);
}

// Round 3
// 2423.230 us; speedup vs baseline: 1.1540x; 1.1540x over previous
//
#include <hip/hip_runtime.h>
#include <hip/hip_bf16.h>
#include <math.h>

#define NP 500000
#define NQ 200000
#define C 64
#define NE 1200000
#define TILE 64
#define PADC 66   // pad 64->66 floats: 4-way (free-ish) LDS banks, 8B-aligned rows

// ---------------- kernels ----------------

// wv[k] = sum_j Wd[k][j] * avd[j]   (folds hd @ avd into x_dst @ wv)
__global__ void wdavd_kernel(const float* __restrict__ Wd,
                             const float* __restrict__ avd,
                             float* __restrict__ wv) {
    int k = threadIdx.x;
    if (k < C) {
        float acc = 0.f;
        #pragma unroll
        for (int j = 0; j < C; ++j) acc = fmaf(Wd[k * C + j], avd[j], acc);
        wv[k] = acc;
    }
}

// hs = x @ W, fused al_s = hs . avs.
// lane = row within a 64-row tile; acc[c] = 64 independent FMA chains in VGPRs;
// W[k][c] comes via uniform scalar loads (k,c wave-uniform); x tile staged in LDS.
__global__ void __launch_bounds__(256) hs_kernel(
        const float* __restrict__ x, const float* __restrict__ W,
        const float* __restrict__ avs,
        __hip_bfloat16* __restrict__ hs, float* __restrict__ al_s, int Ns) {
    __shared__ float xt_all[4][TILE * PADC];
    const int widb = threadIdx.x >> 6;
    const int lane = threadIdx.x & 63;
    float* xt = xt_all[widb];
    const int gwave  = blockIdx.x * 4 + widb;
    const int nwaves = gridDim.x * 4;
    const int ntiles = (Ns + TILE - 1) / TILE;

    for (int tile = gwave; tile < ntiles; tile += nwaves) {
        const int row0  = tile * TILE;
        const int valid = Ns - row0;          // 1..64 (=64 when full)
        const bool full = (valid >= TILE);
        const float* xb = x + (size_t)row0 * C;

        // stage 64x64 floats, coalesced float2; cross-lane LDS writes
        #pragma unroll 8
        for (int i = 0; i < 32; ++i) {
            int e = i * 128 + lane * 2;       // linear element-pair index
            int r = e >> 6, c0 = e & 63;
            float2 v = make_float2(0.f, 0.f);
            if (full || r < valid) v = *(const float2*)(xb + e);
            *(float2*)(xt + r * PADC + c0) = v;
        }
        // same-wave DS write->read: DS pipe is in-order per wave; fence compiler + lgkm
        asm volatile("s_waitcnt lgkmcnt(0)" ::: "memory");

        float acc[C];
        #pragma unroll
        for (int c = 0; c < C; ++c) acc[c] = 0.f;
        const float* xrow = xt + lane * PADC;

        for (int kk = 0; kk < 32; ++kk) {
            float2 xv = *(const float2*)(xrow + 2 * kk);
            #pragma unroll
            for (int c = 0; c < C; ++c)
                acc[c] = fmaf(xv.x, W[(2 * kk) * C + c], acc[c]);
            #pragma unroll
            for (int c = 0; c < C; ++c)
                acc[c] = fmaf(xv.y, W[(2 * kk + 1) * C + c], acc[c]);
        }

        if (full || lane < valid) {
            // al_s: lane holds the whole row -> in-lane dot, no reduce
            float s = 0.f;
            #pragma unroll
            for (int c = 0; c < C; ++c) s = fmaf(acc[c], avs[c], s);
            al_s[row0 + lane] = s;

            // pack row to bf16, 8x dwordx4 stores (rows are 128B-aligned)
            uint32_t pk[32];
            #pragma unroll
            for (int j = 0; j < 32; ++j) {
                __hip_bfloat16 lo = __float2bfloat16(acc[2 * j]);
                __hip_bfloat16 hi = __float2bfloat16(acc[2 * j + 1]);
                pk[j] = (uint32_t)(*(uint16_t*)&lo) | ((uint32_t)(*(uint16_t*)&hi) << 16);
            }
            uint32_t* hrow = (uint32_t*)(hs + (size_t)(row0 + lane) * C);
            #pragma unroll
            for (int j = 0; j < 8; ++j)
                *(uint4*)(hrow + 4 * j) = *(const uint4*)(pk + 4 * j);
        }
    }
}

// al_d[row] = dot(x_dst[row], wv); 16 lanes x float4 per row, 4 rows/wave
__global__ void __launch_bounds__(256) ald_kernel(
        const float* __restrict__ x, const float* __restrict__ wv,
        float* __restrict__ al_d, int Nd) {
    const int lane = threadIdx.x & 63;
    const int sub  = lane & 15;
    const int wid  = (blockIdx.x * 256 + threadIdx.x) >> 6;
    const int nw   = gridDim.x * 4;
    const float4 w4 = *(const float4*)(wv + sub * 4);
    const int nquad = (Nd + 3) >> 2;
    for (int q = wid; q < nquad; q += nw) {
        int row = q * 4 + (lane >> 4);
        float s = 0.f;
        if (row < Nd) {
            float4 v4 = *(const float4*)(x + (size_t)row * C + sub * 4);
            s = v4.x * w4.x + v4.y * w4.y + v4.z * w4.z + v4.w * w4.w;
        }
        s += __shfl_xor(s, 1); s += __shfl_xor(s, 2);
        s += __shfl_xor(s, 4); s += __shfl_xor(s, 8);
        if (sub == 0 && row < Nd) al_d[row] = s;
    }
}

// per edge: e = leaky_relu(al_s[src]+al_d[dst]); ex = exp(e); den[dst] += ex
// (segment-max skipped: softmax is shift-invariant and |e| is small here)
__global__ void __launch_bounds__(256) edge1_kernel(
        const int* __restrict__ src, const int* __restrict__ dst,
        const float* __restrict__ al_s, const float* __restrict__ al_d,
        float* __restrict__ exb, float* __restrict__ den) {
    int e = blockIdx.x * 256 + threadIdx.x;
    if (e >= NE) return;
    int s = src[e], d = dst[e];
    float v = al_s[s] + al_d[d];
    v = v > 0.f ? v : 0.2f * v;
    float xv = expf(v);
    exb[e] = xv;
    atomicAdd(&den[d], xv);
}

// per edge (one wave, lane = channel): agg[dst] += (ex/den[dst]) * hs[src]
__global__ void __launch_bounds__(256) edge2_kernel(
        const int* __restrict__ src, const int* __restrict__ dst,
        const float* __restrict__ exb, const float* __restrict__ den,
        const __hip_bfloat16* __restrict__ hs, float* __restrict__ agg) {
    int lane = threadIdx.x & 63;
    int e = (blockIdx.x * 256 + threadIdx.x) >> 6;
    if (e >= NE) return;
    int s = src[e], d = dst[e];
    float alpha = exb[e] / den[d];
    float v = alpha * __bfloat162float(hs[(size_t)s * C + lane]);
    atomicAdd(&agg[(size_t)d * C + lane], v);
}

// finish: in place fp32, += bias then ELU
__global__ void __launch_bounds__(256) finish_f32_kernel(
        float* __restrict__ agg, const float* __restrict__ bias, int n) {
    int i = blockIdx.x * 256 + threadIdx.x;
    int stride = gridDim.x * 256;
    for (; i < n; i += stride) {
        float v = agg[i] + bias[i & (C - 1)];
        agg[i] = v > 0.f ? v : expm1f(v);
    }
}

// ---------------- host ----------------

static inline int imin(int a, int b) { return a < b ? a : b; }

extern "C" void kernel_launch(void* const* d_in, const int* in_sizes, int n_in,
                              void* d_out, int out_size, void* d_ws, size_t ws_size,
                              hipStream_t stream) {
    const float* x_person  = (const float*)d_in[0];
    const float* x_product = (const float*)d_in[1];
    const int* pv_src = (const int*)d_in[2];
    const int* pv_dst = (const int*)d_in[3];
    const int* vp_src = (const int*)d_in[4];
    const int* vp_dst = (const int*)d_in[5];
    const float* W_src = (const float*)d_in[6];
    const float* W_dst = (const float*)d_in[7];
    const float* a_src = (const float*)d_in[8];
    const float* a_dst = (const float*)d_in[9];
    const float* bias  = (const float*)d_in[10];

    // ---- workspace layout (~250 MB) ----
    float* hp1 = (float*)d_ws;                                    // NP*C fp32
    float* hq1 = hp1 + (size_t)NP * C;                            // NQ*C fp32
    __hip_bfloat16* hs = (__hip_bfloat16*)(hq1 + (size_t)NQ * C); // NP*C bf16
    float* den  = (float*)(hs + (size_t)NP * C);                  // NP
    float* al_s = den + NP;                                       // NP
    float* al_d = al_s + NP;                                      // NP
    float* exb  = al_d + NP;                                      // NE
    float* wv   = exb + NE;                                       // C

    float* out_hp = (float*)d_out;                                // NP*C fp32
    float* out_hq = out_hp + (size_t)NP * C;                      // NQ*C fp32

    auto run_conv = [&](const float* xsrc, int Ns, const float* xdst, int Nd,
                        const int* esrc, const int* edst,
                        int l, int et, float* aggbuf) {
        const float* Ws  = W_src + (size_t)(l * 2 + et) * C * C;
        const float* Wd  = W_dst + (size_t)(l * 2 + et) * C * C;
        const float* avs = a_src + (size_t)(l * 2 + et) * C;
        const float* avd = a_dst + (size_t)(l * 2 + et) * C;

        hipMemsetAsync(den, 0, (size_t)Nd * sizeof(float), stream);
        hipMemsetAsync(aggbuf, 0, (size_t)Nd * C * sizeof(float), stream);

        int ntiles = (Ns + TILE - 1) / TILE;
        wdavd_kernel<<<1, 64, 0, stream>>>(Wd, avd, wv);
        hs_kernel<<<imin((ntiles + 3) / 4, 4096), 256, 0, stream>>>(xsrc, Ws, avs, hs, al_s, Ns);
        ald_kernel<<<imin((((Nd + 3) / 4) + 3) / 4, 2048), 256, 0, stream>>>(xdst, wv, al_d, Nd);
        edge1_kernel<<<(NE + 255) / 256, 256, 0, stream>>>(esrc, edst, al_s, al_d, exb, den);
        edge2_kernel<<<NE / 4, 256, 0, stream>>>(esrc, edst, exb, den, hs, aggbuf);
    };

    // ---- layer 0 (inputs: d_in x tensors; outputs hq1/hp1, ELU applied) ----
    run_conv(x_person, NP, x_product, NQ, pv_src, pv_dst, 0, 0, hq1);
    finish_f32_kernel<<<2048, 256, 0, stream>>>(hq1, bias + 0 * C, NQ * C);
    run_conv(x_product, NQ, x_person, NP, vp_src, vp_dst, 0, 1, hp1);
    finish_f32_kernel<<<2048, 256, 0, stream>>>(hp1, bias + 1 * C, NP * C);

    // ---- layer 1 (inputs hp1/hq1; aggregate straight into fp32 d_out) ----
    run_conv(hp1, NP, hq1, NQ, pv_src, pv_dst, 1, 0, out_hq);
    finish_f32_kernel<<<2048, 256, 0, stream>>>(out_hq, bias + 2 * C, NQ * C);
    run_conv(hq1, NQ, hp1, NP, vp_src, vp_dst, 1, 1, out_hp);
    finish_f32_kernel<<<2048, 256, 0, stream>>>(out_hp, bias + 3 * C, NP * C);
}

// Round 4
// 2199.073 us; speedup vs baseline: 1.2716x; 1.1019x over previous
//
#include <hip/hip_runtime.h>
#include <hip/hip_bf16.h>
#include <math.h>

#define NP 500000
#define NQ 200000
#define C 64
#define NE 1200000
#define TILE 64
#define PADC 66   // pad 64->66 floats: kills power-of-2 LDS bank stride

// ---------------- CSR build ----------------

// cnt[d]++ per edge (cnt buffer later becomes the scatter cursor)
__global__ void __launch_bounds__(256) hist_kernel(
        const int* __restrict__ dst, int* __restrict__ cnt) {
    int e = blockIdx.x * 256 + threadIdx.x;
    if (e < NE) atomicAdd(&cnt[dst[e]], 1);
}

// exclusive alloc: start[i] = running base; cnt[i] rewritten in-place as cursor
__global__ void __launch_bounds__(256) alloc_kernel(
        int* __restrict__ cnt, int* __restrict__ start,
        int* __restrict__ gcur, int n) {
    int i = blockIdx.x * 256 + threadIdx.x;
    int lane = threadIdx.x & 63;
    int c = (i < n) ? cnt[i] : 0;
    int sc = c;                               // inclusive wave scan
    #pragma unroll
    for (int off = 1; off < 64; off <<= 1) {
        int t = __shfl_up(sc, off);
        if (lane >= off) sc += t;
    }
    int total = __shfl(sc, 63);
    int base = 0;
    if (lane == 63) base = atomicAdd(gcur, total);
    base = __shfl(base, 63);
    int st = base + sc - c;                   // exclusive
    if (i < n) { start[i] = st; cnt[i] = st; }
}

// srcv[pos] = src[e], grouped by dst (order within a group arbitrary)
__global__ void __launch_bounds__(256) scatter_kernel(
        const int* __restrict__ src, const int* __restrict__ dst,
        int* __restrict__ cur, int* __restrict__ srcv) {
    int e = blockIdx.x * 256 + threadIdx.x;
    if (e >= NE) return;
    int pos = atomicAdd(&cur[dst[e]], 1);
    srcv[pos] = src[e];
}

// ---------------- dense kernels ----------------

// wv[k] = sum_j Wd[k][j] * avd[j]   (folds hd @ avd into x_dst @ wv)
__global__ void wdavd_kernel(const float* __restrict__ Wd,
                             const float* __restrict__ avd,
                             float* __restrict__ wv) {
    int k = threadIdx.x;
    if (k < C) {
        float acc = 0.f;
        #pragma unroll
        for (int j = 0; j < C; ++j) acc = fmaf(Wd[k * C + j], avd[j], acc);
        wv[k] = acc;
    }
}

// hs = x @ W, fused al_s = hs . avs. lane = row in a 64-row LDS tile;
// acc[c] = 64 independent FMA chains; W via wave-uniform loads.
__global__ void __launch_bounds__(256) hs_kernel(
        const float* __restrict__ x, const float* __restrict__ W,
        const float* __restrict__ avs,
        __hip_bfloat16* __restrict__ hs, float* __restrict__ al_s, int Ns) {
    __shared__ float xt_all[4][TILE * PADC];
    const int widb = threadIdx.x >> 6;
    const int lane = threadIdx.x & 63;
    float* xt = xt_all[widb];
    const int gwave  = blockIdx.x * 4 + widb;
    const int nwaves = gridDim.x * 4;
    const int ntiles = (Ns + TILE - 1) / TILE;

    for (int tile = gwave; tile < ntiles; tile += nwaves) {
        const int row0  = tile * TILE;
        const int valid = Ns - row0;
        const bool full = (valid >= TILE);
        const float* xb = x + (size_t)row0 * C;

        #pragma unroll 8
        for (int i = 0; i < 32; ++i) {
            int e = i * 128 + lane * 2;
            int r = e >> 6, c0 = e & 63;
            float2 v = make_float2(0.f, 0.f);
            if (full || r < valid) v = *(const float2*)(xb + e);
            *(float2*)(xt + r * PADC + c0) = v;
        }
        asm volatile("s_waitcnt lgkmcnt(0)" ::: "memory");

        float acc[C];
        #pragma unroll
        for (int c = 0; c < C; ++c) acc[c] = 0.f;
        const float* xrow = xt + lane * PADC;

        for (int kk = 0; kk < 32; ++kk) {
            float2 xv = *(const float2*)(xrow + 2 * kk);
            #pragma unroll
            for (int c = 0; c < C; ++c)
                acc[c] = fmaf(xv.x, W[(2 * kk) * C + c], acc[c]);
            #pragma unroll
            for (int c = 0; c < C; ++c)
                acc[c] = fmaf(xv.y, W[(2 * kk + 1) * C + c], acc[c]);
        }

        if (full || lane < valid) {
            float s = 0.f;
            #pragma unroll
            for (int c = 0; c < C; ++c) s = fmaf(acc[c], avs[c], s);
            al_s[row0 + lane] = s;

            uint32_t pk[32];
            #pragma unroll
            for (int j = 0; j < 32; ++j) {
                __hip_bfloat16 lo = __float2bfloat16(acc[2 * j]);
                __hip_bfloat16 hi = __float2bfloat16(acc[2 * j + 1]);
                pk[j] = (uint32_t)(*(uint16_t*)&lo) | ((uint32_t)(*(uint16_t*)&hi) << 16);
            }
            uint32_t* hrow = (uint32_t*)(hs + (size_t)(row0 + lane) * C);
            #pragma unroll
            for (int j = 0; j < 8; ++j)
                *(uint4*)(hrow + 4 * j) = *(const uint4*)(pk + 4 * j);
        }
    }
}

// al_d[row] = dot(x_dst[row], wv); 16 lanes x float4 per row
__global__ void __launch_bounds__(256) ald_kernel(
        const float* __restrict__ x, const float* __restrict__ wv,
        float* __restrict__ al_d, int Nd) {
    const int lane = threadIdx.x & 63;
    const int sub  = lane & 15;
    const int wid  = (blockIdx.x * 256 + threadIdx.x) >> 6;
    const int nw   = gridDim.x * 4;
    const float4 w4 = *(const float4*)(wv + sub * 4);
    const int nquad = (Nd + 3) >> 2;
    for (int q = wid; q < nquad; q += nw) {
        int row = q * 4 + (lane >> 4);
        float s = 0.f;
        if (row < Nd) {
            float4 v4 = *(const float4*)(x + (size_t)row * C + sub * 4);
            s = v4.x * w4.x + v4.y * w4.y + v4.z * w4.z + v4.w * w4.w;
        }
        s += __shfl_xor(s, 1); s += __shfl_xor(s, 2);
        s += __shfl_xor(s, 4); s += __shfl_xor(s, 8);
        if (sub == 0 && row < Nd) al_d[row] = s;
    }
}

// ---------------- fused GAT aggregation (CSR, atomic-free) ----------------
// wave per dst row, lane = channel. pass 1: den; pass 2: acc; write ELU(acc+bias).
// segment-max skipped: softmax is shift-invariant and |e| is small here.
__global__ void __launch_bounds__(256) gat_csr_kernel(
        const int* __restrict__ start, const int* __restrict__ endp,
        const int* __restrict__ srcv,
        const float* __restrict__ al_s, const float* __restrict__ al_d,
        const __hip_bfloat16* __restrict__ hs, const float* __restrict__ bias,
        float* __restrict__ out, int Nd) {
    const int lane = threadIdx.x & 63;
    const int wid  = (blockIdx.x * 256 + threadIdx.x) >> 6;
    const int nw   = gridDim.x * 4;
    const float b  = bias[lane];
    for (int d = wid; d < Nd; d += nw) {
        const int st = start[d], en = endp[d];
        const float ad = al_d[d];
        float den = 0.f;
        for (int j = st; j < en; ++j) {
            float v = al_s[srcv[j]] + ad;
            v = v > 0.f ? v : 0.2f * v;
            den += expf(v);
        }
        const float rden = (en > st) ? 1.f / den : 0.f;
        float acc = 0.f;
        for (int j = st; j < en; ++j) {
            int s = srcv[j];
            float v = al_s[s] + ad;
            v = v > 0.f ? v : 0.2f * v;
            float w = expf(v) * rden;
            acc = fmaf(w, __bfloat162float(hs[(size_t)s * C + lane]), acc);
        }
        float o = acc + b;
        out[(size_t)d * C + lane] = o > 0.f ? o : expm1f(o);
    }
}

// ---------------- host ----------------

static inline int imin(int a, int b) { return a < b ? a : b; }

extern "C" void kernel_launch(void* const* d_in, const int* in_sizes, int n_in,
                              void* d_out, int out_size, void* d_ws, size_t ws_size,
                              hipStream_t stream) {
    const float* x_person  = (const float*)d_in[0];
    const float* x_product = (const float*)d_in[1];
    const int* pv_src = (const int*)d_in[2];
    const int* pv_dst = (const int*)d_in[3];
    const int* vp_src = (const int*)d_in[4];
    const int* vp_dst = (const int*)d_in[5];
    const float* W_src = (const float*)d_in[6];
    const float* W_dst = (const float*)d_in[7];
    const float* a_src = (const float*)d_in[8];
    const float* a_dst = (const float*)d_in[9];
    const float* bias  = (const float*)d_in[10];

    float* out_hp = (float*)d_out;                                // NP*C fp32
    float* out_hq = out_hp + (size_t)NP * C;                      // NQ*C fp32

    // ---- workspace (~134 MB); hp1 aliases out_hp (safe: last write wins) ----
    float* hp1 = out_hp;
    float* hq1 = (float*)d_ws;                                    // NQ*C fp32
    __hip_bfloat16* hs = (__hip_bfloat16*)(hq1 + (size_t)NQ * C); // NP*C bf16
    float* al_s = (float*)(hs + (size_t)NP * C);                  // NP
    float* al_d = al_s + NP;                                      // NP
    float* wv   = al_d + NP;                                      // C
    int* gcur   = (int*)(wv + C);                                 // 2
    int* start_pv = gcur + 2;                                     // NQ
    int* cur_pv   = start_pv + NQ;                                // NQ (cnt->cursor->end)
    int* srcv_pv  = cur_pv + NQ;                                  // NE
    int* start_vp = srcv_pv + NE;                                 // NP
    int* cur_vp   = start_vp + NP;                                // NP
    int* srcv_vp  = cur_vp + NP;                                  // NE

    // ---- build CSR for both edge types (reused by both layers) ----
    hipMemsetAsync(cur_pv, 0, (size_t)NQ * sizeof(int), stream);
    hipMemsetAsync(cur_vp, 0, (size_t)NP * sizeof(int), stream);
    hipMemsetAsync(gcur, 0, 2 * sizeof(int), stream);
    hist_kernel<<<(NE + 255) / 256, 256, 0, stream>>>(pv_dst, cur_pv);
    hist_kernel<<<(NE + 255) / 256, 256, 0, stream>>>(vp_dst, cur_vp);
    alloc_kernel<<<(NQ + 255) / 256, 256, 0, stream>>>(cur_pv, start_pv, gcur + 0, NQ);
    alloc_kernel<<<(NP + 255) / 256, 256, 0, stream>>>(cur_vp, start_vp, gcur + 1, NP);
    scatter_kernel<<<(NE + 255) / 256, 256, 0, stream>>>(pv_src, pv_dst, cur_pv, srcv_pv);
    scatter_kernel<<<(NE + 255) / 256, 256, 0, stream>>>(vp_src, vp_dst, cur_vp, srcv_vp);
    // after scatter, cur_*[d] == end offset for row d

    auto run_conv = [&](const float* xsrc, int Ns, const float* xdst, int Nd,
                        const int* startA, const int* endA, const int* srcvA,
                        int l, int et, float* outbuf) {
        const float* Ws  = W_src + (size_t)(l * 2 + et) * C * C;
        const float* Wd  = W_dst + (size_t)(l * 2 + et) * C * C;
        const float* avs = a_src + (size_t)(l * 2 + et) * C;
        const float* avd = a_dst + (size_t)(l * 2 + et) * C;
        const float* bia = bias  + (size_t)(l * 2 + et) * C;

        int ntiles = (Ns + TILE - 1) / TILE;
        wdavd_kernel<<<1, 64, 0, stream>>>(Wd, avd, wv);
        hs_kernel<<<imin((ntiles + 3) / 4, 4096), 256, 0, stream>>>(xsrc, Ws, avs, hs, al_s, Ns);
        ald_kernel<<<imin((((Nd + 3) / 4) + 3) / 4, 2048), 256, 0, stream>>>(xdst, wv, al_d, Nd);
        gat_csr_kernel<<<imin((Nd + 3) / 4, 16384), 256, 0, stream>>>(
            startA, endA, srcvA, al_s, al_d, hs, bia, outbuf, Nd);
    };

    // ---- layer 0 ----
    run_conv(x_person, NP, x_product, NQ, start_pv, cur_pv, srcv_pv, 0, 0, hq1);
    run_conv(x_product, NQ, x_person, NP, start_vp, cur_vp, srcv_vp, 0, 1, hp1);

    // ---- layer 1 (writes final d_out; ELU fused in gat_csr) ----
    run_conv(hp1, NP, hq1, NQ, start_pv, cur_pv, srcv_pv, 1, 0, out_hq);
    run_conv(hq1, NQ, hp1, NP, start_vp, cur_vp, srcv_vp, 1, 1, out_hp);
}